// Round 18
// baseline (2232.597 us; speedup 1.0000x reference)
//
#include <hip/hip_runtime.h>

#define B_ 16
#define S_ 4096
#define D_ 256
#define H_ 256

typedef _Float16 h2 __attribute__((ext_vector_type(2)));
typedef _Float16 h4 __attribute__((ext_vector_type(4)));
typedef _Float16 h8 __attribute__((ext_vector_type(8)));
typedef _Float16 h8v __attribute__((ext_vector_type(8)));
typedef float f4 __attribute__((ext_vector_type(4)));

// packed f16 FMA: d = a*b + c per 16-bit lane (VOP3P, full-rate)
static __device__ __forceinline__ h2 pkfma(h2 a, h2 b, h2 c) {
    asm("v_pk_fma_f16 %0, %1, %2, %0" : "+v"(c) : "v"(a), "v"(b));
    return c;
}
static __device__ __forceinline__ h2 pkadd(h2 a, h2 b) {
    h2 d;
    asm("v_pk_add_f16 %0, %1, %2" : "=v"(d) : "v"(a), "v"(b));
    return d;
}

template <int CTRL>
static __device__ __forceinline__ float dpp_qp(float v) {
    int r = __builtin_amdgcn_update_dpp(0, __float_as_int(v), CTRL, 0xF, 0xF, true);
    return __int_as_float(r);
}
#define DPP_XOR1 0xB1   // quad_perm [1,0,3,2]
#define DPP_XOR2 0x4E   // quad_perm [2,3,0,1]

// LDS-only barrier: drain LDS ops, NOT vmcnt (T4).
static __device__ __forceinline__ void lds_barrier() {
    asm volatile("s_waitcnt lgkmcnt(0)" ::: "memory");
    __builtin_amdgcn_s_barrier();
}

// swizzled f16-index for h element i in a 256-entry LDS buffer (R4/R8-verified).
static __device__ __forceinline__ int swz(int i) {
    const int s = i >> 6, r = (i >> 3) & 7, e = i & 7;
    return 64 * s + 8 * ((r + 2 * s) & 7) + e;
}

// Kernel 1: xp = x @ Wx + b via MFMA f16 (round-14 version, verified).
__global__ __launch_bounds__(256, 1) void xproj_kernel(
    const float* __restrict__ x, const float* __restrict__ Wx,
    const float* __restrict__ bias, float* __restrict__ out)
{
    __shared__ __align__(16) _Float16 xs[16 * 272];
    const int tid = threadIdx.x;
    const int l   = tid & 63;
    const int wav = tid >> 6;
    const int lc  = l & 15;
    const int kg  = l >> 4;
    const long long row0 = (long long)blockIdx.x * 256;

    h8v bf[4][8];
    #pragma unroll
    for (int nt = 0; nt < 4; ++nt) {
        const int j = 64 * wav + 16 * nt + lc;
        #pragma unroll
        for (int ks = 0; ks < 8; ++ks) {
            #pragma unroll
            for (int e = 0; e < 8; ++e)
                bf[nt][ks][e] = (_Float16)Wx[(32 * ks + 8 * kg + e) * H_ + j];
        }
    }
    float bvv[4];
    #pragma unroll
    for (int nt = 0; nt < 4; ++nt)
        bvv[nt] = bias[64 * wav + 16 * nt + lc];

    f4 pre[4];
    #pragma unroll
    for (int k4 = 0; k4 < 4; ++k4)
        pre[k4] = *(const f4*)&x[(row0 + wav + 4 * k4) * D_ + 4 * l];

    for (int it = 0; it < 16; ++it) {
        const long long r0 = row0 + it * 16;

        __syncthreads();
        #pragma unroll
        for (int k4 = 0; k4 < 4; ++k4) {
            h4 hv;
            hv[0] = (_Float16)pre[k4].x;
            hv[1] = (_Float16)pre[k4].y;
            hv[2] = (_Float16)pre[k4].z;
            hv[3] = (_Float16)pre[k4].w;
            *(h4*)&xs[(wav + 4 * k4) * 272 + 4 * l] = hv;
        }
        __syncthreads();

        if (it + 1 < 16) {
            const long long rn = row0 + (it + 1) * 16;
            #pragma unroll
            for (int k4 = 0; k4 < 4; ++k4)
                pre[k4] = *(const f4*)&x[(rn + wav + 4 * k4) * D_ + 4 * l];
        }

        f4 acc[4];
        #pragma unroll
        for (int nt = 0; nt < 4; ++nt)
            acc[nt] = (f4){0.f, 0.f, 0.f, 0.f};

        #pragma unroll
        for (int ks = 0; ks < 8; ++ks) {
            h8v af = *(const h8v*)&xs[lc * 272 + 32 * ks + 8 * kg];
            acc[0] = __builtin_amdgcn_mfma_f32_16x16x32_f16(af, bf[0][ks], acc[0], 0, 0, 0);
            acc[1] = __builtin_amdgcn_mfma_f32_16x16x32_f16(af, bf[1][ks], acc[1], 0, 0, 0);
            acc[2] = __builtin_amdgcn_mfma_f32_16x16x32_f16(af, bf[2][ks], acc[2], 0, 0, 0);
            acc[3] = __builtin_amdgcn_mfma_f32_16x16x32_f16(af, bf[3][ks], acc[3], 0, 0, 0);
        }

        #pragma unroll
        for (int nt = 0; nt < 4; ++nt) {
            const int j = 64 * wav + 16 * nt + lc;
            #pragma unroll
            for (int r = 0; r < 4; ++r)
                out[(r0 + 4 * kg + r) * H_ + j] = acc[nt][r] + bvv[nt];
        }
    }
}

// Kernel 2: sequential scan — R8 structure (best: 985 cy/step) with the
// dot2 inner product replaced by v_pk_fma_f16 (packed f16 accumulate,
// 2 chains per output j; combined via pk_add + 2 cvt in f32).
// One block (CU) per batch, 256 threads, split-K x4 + DPP quad reduce,
// swizzled h LDS, xp ring distance 4, lgkm-only barrier.
__global__ __launch_bounds__(256, 1) void scan_kernel(
    const float* __restrict__ Wh, const float* __restrict__ state0,
    float* __restrict__ out)
{
    __shared__ __align__(16) _Float16 hbuf[2][H_];
    const int tid = threadIdx.x;
    const int s = tid & 3;          // i-slice
    const int q = tid >> 2;         // j-group
    const int b = blockIdx.x;
    const bool o1 = (s & 1) != 0;
    const bool o2 = (s & 2) != 0;

    // W[i][j] for i in [64s,64s+64), j in [4q,4q+4), packed as h2 i-pairs.
    h2 w[4][32];
    #pragma unroll
    for (int jj = 0; jj < 4; ++jj) {
        const int j = 4 * q + jj;
        #pragma unroll
        for (int ii = 0; ii < 32; ++ii) {
            const int i = 64 * s + 2 * ii;
            h2 p;
            p[0] = (_Float16)Wh[(long long)i * H_ + j];
            p[1] = (_Float16)Wh[(long long)(i + 1) * H_ + j];
            w[jj][ii] = p;
        }
    }

    hbuf[0][swz(tid)] = (_Float16)state0[b * H_ + tid];

    float* __restrict__ outb = out + (long long)b * S_ * H_;

    // xp prefetch ring, distance 4 (static indices via unroll-4)
    float xr[4];
    #pragma unroll
    for (int k = 0; k < 4; ++k)
        xr[k] = outb[(long long)k * H_ + tid];
    __syncthreads();

    const h2 zz = {(_Float16)0.f, (_Float16)0.f};

    // chunk r holds h[64s+8r .. +8] at f16-pos 64s + 8*((r+2s)&7)
    #pragma unroll 4
    for (int st = 0; st < S_; ++st) {
        const int p = st & 1;
        const _Float16* hb = hbuf[p];

        h8 hv[8];
        #pragma unroll
        for (int r = 0; r < 8; ++r)
            hv[r] = *(const h8*)&hb[64 * s + 8 * ((r + 2 * s) & 7)];

        // packed-f16 accumulation: 2 chains per j (even/odd r)
        h2 a0a = zz, a0b = zz, a1a = zz, a1b = zz;
        h2 a2a = zz, a2b = zz, a3a = zz, a3b = zz;
        #pragma unroll
        for (int r = 0; r < 8; ++r) {
            union { h8 v; h2 pr[4]; } u;
            u.v = hv[r];
            #pragma unroll
            for (int m = 0; m < 4; ++m) {
                const int ii = 4 * r + m;
                if ((r & 1) == 0) {
                    a0a = pkfma(u.pr[m], w[0][ii], a0a);
                    a1a = pkfma(u.pr[m], w[1][ii], a1a);
                    a2a = pkfma(u.pr[m], w[2][ii], a2a);
                    a3a = pkfma(u.pr[m], w[3][ii], a3a);
                } else {
                    a0b = pkfma(u.pr[m], w[0][ii], a0b);
                    a1b = pkfma(u.pr[m], w[1][ii], a1b);
                    a2b = pkfma(u.pr[m], w[2][ii], a2b);
                    a3b = pkfma(u.pr[m], w[3][ii], a3b);
                }
            }
        }
        // combine chains: pk_add then f32 horizontal
        h2 s0 = pkadd(a0a, a0b), s1 = pkadd(a1a, a1b);
        h2 s2 = pkadd(a2a, a2b), s3 = pkadd(a3a, a3b);
        float acc0 = (float)s0[0] + (float)s0[1];
        float acc1 = (float)s1[0] + (float)s1[1];
        float acc2 = (float)s2[0] + (float)s2[1];
        float acc3 = (float)s3[0] + (float)s3[1];

        // reduce-scatter across the 4 slice-threads (pure VALU DPP)
        float vA = o1 ? acc1 : acc0;
        float vB = o1 ? acc3 : acc2;
        float sA = o1 ? acc0 : acc1;
        float sB = o1 ? acc2 : acc3;
        vA += dpp_qp<DPP_XOR1>(sA);
        vB += dpp_qp<DPP_XOR1>(sB);
        float v   = o2 ? vB : vA;
        float snd = o2 ? vA : vB;
        v += dpp_qp<DPP_XOR2>(snd);
        // v = full dot for j = 4q + s = tid

        const float pre = v + xr[st & 3];
        const float e = __builtin_amdgcn_exp2f(pre * 2.8853900817779268f);
        const float hn = fmaf(-2.f, __builtin_amdgcn_rcpf(e + 1.f), 1.f);

        outb[(long long)st * H_ + tid] = hn;       // stays in flight
        hbuf[p ^ 1][swz(tid)] = (_Float16)hn;      // publish h for t+1

        const int nt = st + 4;
        xr[st & 3] = (nt < S_) ? outb[(long long)nt * H_ + tid] : 0.f;
        lds_barrier();   // lgkmcnt(0) + s_barrier — NO vmcnt drain
    }
}

extern "C" void kernel_launch(void* const* d_in, const int* in_sizes, int n_in,
                              void* d_out, int out_size, void* d_ws, size_t ws_size,
                              hipStream_t stream) {
    const float* x  = (const float*)d_in[0];   // [B,S,D]
    const float* s0 = (const float*)d_in[1];   // [B,H]
    const float* Wx = (const float*)d_in[2];   // [D,H]
    const float* Wh = (const float*)d_in[3];   // [H,H]
    const float* bv = (const float*)d_in[4];   // [H]
    float* out = (float*)d_out;                // [B,S,H]

    xproj_kernel<<<dim3((B_ * S_) / 256), dim3(256), 0, stream>>>(x, Wx, bv, out);
    scan_kernel<<<dim3(B_), dim3(256), 0, stream>>>(Wh, s0, out);
}

// Round 19
// 1702.395 us; speedup vs baseline: 1.3114x; 1.3114x over previous
//
#include <hip/hip_runtime.h>

#define B_ 16
#define S_ 4096
#define D_ 256
#define H_ 256

typedef _Float16 h2 __attribute__((ext_vector_type(2)));
typedef _Float16 h4 __attribute__((ext_vector_type(4)));
typedef _Float16 h8 __attribute__((ext_vector_type(8)));
typedef _Float16 h8v __attribute__((ext_vector_type(8)));
typedef float f4 __attribute__((ext_vector_type(4)));

static __device__ __forceinline__ float fdot2f(h2 a, h2 b, float c) {
    return __builtin_amdgcn_fdot2(a, b, c, false);
}

template <int CTRL>
static __device__ __forceinline__ float dpp_qp(float v) {
    int r = __builtin_amdgcn_update_dpp(0, __float_as_int(v), CTRL, 0xF, 0xF, true);
    return __int_as_float(r);
}
#define DPP_XOR1 0xB1   // quad_perm [1,0,3,2]
#define DPP_XOR2 0x4E   // quad_perm [2,3,0,1]

// LDS-only barrier: drain LDS ops, NOT vmcnt (T4).
static __device__ __forceinline__ void lds_barrier() {
    asm volatile("s_waitcnt lgkmcnt(0)" ::: "memory");
    __builtin_amdgcn_s_barrier();
}

// swizzled f16-index for h element i in a 256-entry LDS buffer (R4/R8-verified).
static __device__ __forceinline__ int swz(int i) {
    const int s = i >> 6, r = (i >> 3) & 7, e = i & 7;
    return 64 * s + 8 * ((r + 2 * s) & 7) + e;
}

// Kernel 1: xp = x @ Wx + b via MFMA f16 (round-14 version, verified).
__global__ __launch_bounds__(256, 1) void xproj_kernel(
    const float* __restrict__ x, const float* __restrict__ Wx,
    const float* __restrict__ bias, float* __restrict__ out)
{
    __shared__ __align__(16) _Float16 xs[16 * 272];
    const int tid = threadIdx.x;
    const int l   = tid & 63;
    const int wav = tid >> 6;      // 0..3
    const int lc  = l & 15;
    const int kg  = l >> 4;        // 0..3
    const long long row0 = (long long)blockIdx.x * 256;

    h8v bf[4][8];
    #pragma unroll
    for (int nt = 0; nt < 4; ++nt) {
        const int j = 64 * wav + 16 * nt + lc;
        #pragma unroll
        for (int ks = 0; ks < 8; ++ks) {
            #pragma unroll
            for (int e = 0; e < 8; ++e)
                bf[nt][ks][e] = (_Float16)Wx[(32 * ks + 8 * kg + e) * H_ + j];
        }
    }
    float bvv[4];
    #pragma unroll
    for (int nt = 0; nt < 4; ++nt)
        bvv[nt] = bias[64 * wav + 16 * nt + lc];

    f4 pre[4];
    #pragma unroll
    for (int k4 = 0; k4 < 4; ++k4)
        pre[k4] = *(const f4*)&x[(row0 + wav + 4 * k4) * D_ + 4 * l];

    for (int it = 0; it < 16; ++it) {
        const long long r0 = row0 + it * 16;

        __syncthreads();
        #pragma unroll
        for (int k4 = 0; k4 < 4; ++k4) {
            h4 hv;
            hv[0] = (_Float16)pre[k4].x;
            hv[1] = (_Float16)pre[k4].y;
            hv[2] = (_Float16)pre[k4].z;
            hv[3] = (_Float16)pre[k4].w;
            *(h4*)&xs[(wav + 4 * k4) * 272 + 4 * l] = hv;
        }
        __syncthreads();

        if (it + 1 < 16) {
            const long long rn = row0 + (it + 1) * 16;
            #pragma unroll
            for (int k4 = 0; k4 < 4; ++k4)
                pre[k4] = *(const f4*)&x[(rn + wav + 4 * k4) * D_ + 4 * l];
        }

        f4 acc[4];
        #pragma unroll
        for (int nt = 0; nt < 4; ++nt)
            acc[nt] = (f4){0.f, 0.f, 0.f, 0.f};

        #pragma unroll
        for (int ks = 0; ks < 8; ++ks) {
            h8v af = *(const h8v*)&xs[lc * 272 + 32 * ks + 8 * kg];
            acc[0] = __builtin_amdgcn_mfma_f32_16x16x32_f16(af, bf[0][ks], acc[0], 0, 0, 0);
            acc[1] = __builtin_amdgcn_mfma_f32_16x16x32_f16(af, bf[1][ks], acc[1], 0, 0, 0);
            acc[2] = __builtin_amdgcn_mfma_f32_16x16x32_f16(af, bf[2][ks], acc[2], 0, 0, 0);
            acc[3] = __builtin_amdgcn_mfma_f32_16x16x32_f16(af, bf[3][ks], acc[3], 0, 0, 0);
        }

        #pragma unroll
        for (int nt = 0; nt < 4; ++nt) {
            const int j = 64 * wav + 16 * nt + lc;
            #pragma unroll
            for (int r = 0; r < 4; ++r)
                out[(r0 + 4 * kg + r) * H_ + j] = acc[nt][r] + bvv[nt];
        }
    }
}

// Kernel 2: sequential scan (round-8 version, best measured: ~1680 us).
// One block (CU) per batch, 256 threads. Split-K x4 + DPP quad reduce,
// swizzled h LDS, xp register ring distance 4, lgkm-only barrier.
__global__ __launch_bounds__(256, 1) void scan_kernel(
    const float* __restrict__ Wh, const float* __restrict__ state0,
    float* __restrict__ out)
{
    __shared__ __align__(16) _Float16 hbuf[2][H_];
    const int tid = threadIdx.x;
    const int s = tid & 3;          // i-slice
    const int q = tid >> 2;         // j-group
    const int b = blockIdx.x;
    const bool o1 = (s & 1) != 0;
    const bool o2 = (s & 2) != 0;

    // W[i][j] for i in [64s,64s+64), j in [4q,4q+4), packed as h2 i-pairs.
    h2 w[4][32];
    #pragma unroll
    for (int jj = 0; jj < 4; ++jj) {
        const int j = 4 * q + jj;
        #pragma unroll
        for (int ii = 0; ii < 32; ++ii) {
            const int i = 64 * s + 2 * ii;
            h2 p;
            p[0] = (_Float16)Wh[(long long)i * H_ + j];
            p[1] = (_Float16)Wh[(long long)(i + 1) * H_ + j];
            w[jj][ii] = p;
        }
    }

    hbuf[0][swz(tid)] = (_Float16)state0[b * H_ + tid];

    float* __restrict__ outb = out + (long long)b * S_ * H_;

    // xp prefetch ring, distance 4 (static indices via unroll-4)
    float xr[4];
    #pragma unroll
    for (int k = 0; k < 4; ++k)
        xr[k] = outb[(long long)k * H_ + tid];
    __syncthreads();

    // chunk r holds h[64s+8r .. +8] at f16-pos 64s + 8*((r+2s)&7)
    #pragma unroll 4
    for (int st = 0; st < S_; ++st) {
        const int p = st & 1;
        const _Float16* hb = hbuf[p];

        h8 hv[8];
        #pragma unroll
        for (int r = 0; r < 8; ++r)
            hv[r] = *(const h8*)&hb[64 * s + 8 * ((r + 2 * s) & 7)];

        float acc0 = 0.f, acc1 = 0.f, acc2 = 0.f, acc3 = 0.f;
        #pragma unroll
        for (int r = 0; r < 8; ++r) {
            union { h8 v; h2 pr[4]; } u;
            u.v = hv[r];
            #pragma unroll
            for (int m = 0; m < 4; ++m) {
                const int ii = 4 * r + m;
                acc0 = fdot2f(u.pr[m], w[0][ii], acc0);
                acc1 = fdot2f(u.pr[m], w[1][ii], acc1);
                acc2 = fdot2f(u.pr[m], w[2][ii], acc2);
                acc3 = fdot2f(u.pr[m], w[3][ii], acc3);
            }
        }

        // reduce-scatter across the 4 slice-threads (pure VALU DPP)
        float vA = o1 ? acc1 : acc0;
        float vB = o1 ? acc3 : acc2;
        float sA = o1 ? acc0 : acc1;
        float sB = o1 ? acc2 : acc3;
        vA += dpp_qp<DPP_XOR1>(sA);
        vB += dpp_qp<DPP_XOR1>(sB);
        float v   = o2 ? vB : vA;
        float snd = o2 ? vA : vB;
        v += dpp_qp<DPP_XOR2>(snd);
        // v = full dot for j = 4q + s = tid

        const float pre = v + xr[st & 3];
        const float e = __builtin_amdgcn_exp2f(pre * 2.8853900817779268f);
        const float hn = fmaf(-2.f, __builtin_amdgcn_rcpf(e + 1.f), 1.f);

        outb[(long long)st * H_ + tid] = hn;       // stays in flight
        hbuf[p ^ 1][swz(tid)] = (_Float16)hn;      // publish h for t+1

        const int nt = st + 4;
        xr[st & 3] = (nt < S_) ? outb[(long long)nt * H_ + tid] : 0.f;
        lds_barrier();   // lgkmcnt(0) + s_barrier — NO vmcnt drain
    }
}

extern "C" void kernel_launch(void* const* d_in, const int* in_sizes, int n_in,
                              void* d_out, int out_size, void* d_ws, size_t ws_size,
                              hipStream_t stream) {
    const float* x  = (const float*)d_in[0];   // [B,S,D]
    const float* s0 = (const float*)d_in[1];   // [B,H]
    const float* Wx = (const float*)d_in[2];   // [D,H]
    const float* Wh = (const float*)d_in[3];   // [H,H]
    const float* bv = (const float*)d_in[4];   // [H]
    float* out = (float*)d_out;                // [B,S,H]

    xproj_kernel<<<dim3((B_ * S_) / 256), dim3(256), 0, stream>>>(x, Wx, bv, out);
    scan_kernel<<<dim3(B_), dim3(256), 0, stream>>>(Wh, s0, out);
}